// Round 11
// baseline (725.612 us; speedup 1.0000x reference)
//
#include <hip/hip_runtime.h>

#define D 2048
#define T 1024
#define NG 6144            // 3 * D
#define KC_BLOCKS 128      // one 16-col j-group per block

typedef short bf16x8 __attribute__((ext_vector_type(8)));
typedef float f32x4 __attribute__((ext_vector_type(4)));

__device__ __forceinline__ float sigf(float x) {
    return 1.0f / (1.0f + __expf(-x));
}
__device__ __forceinline__ float tanhfast(float x) {
    float e = __expf(-2.0f * fabsf(x));
    float t = (1.0f - e) / (1.0f + e);
    return copysignf(t, x);
}
// fp32 -> bf16 round-to-nearest-even
__device__ __forceinline__ unsigned short f2bf(float x) {
    unsigned int u = __float_as_uint(x);
    return (unsigned short)((u + 0x7FFFu + ((u >> 16) & 1u)) >> 16);
}
__device__ __forceinline__ float bf2f(unsigned short h) {
    return __uint_as_float((unsigned int)h << 16);
}

// coherent-bypass 16B H-fragment load: 2 x relaxed agent-scope u64 atomic
// loads. Same primitive as the barrier flag polls (R9/R10-proven to observe
// remote sc-stores without any cache-inv fence). Compiler tracks vmcnt.
__device__ __forceinline__ bf16x8 ld_h_sc(const unsigned short* p) {
    const unsigned long long* q = (const unsigned long long*)p;
    union { unsigned long long u[2]; bf16x8 v; } r;
    r.u[0] = __hip_atomic_load(q,     __ATOMIC_RELAXED, __HIP_MEMORY_SCOPE_AGENT);
    r.u[1] = __hip_atomic_load(q + 1, __ATOMIC_RELAXED, __HIP_MEMORY_SCOPE_AGENT);
    return r.v;
}

// ---------------------------------------------------------------------------
// kX: X fp32 -> bf16
// ---------------------------------------------------------------------------
__global__ void kX(const float* __restrict__ X, unsigned short* __restrict__ Xh) {
    int idx = blockIdx.x * 256 + threadIdx.x;
    const int total = T * D / 4;
    for (; idx < total; idx += gridDim.x * 256) {
        float4 v = *(const float4*)&X[idx * 4];
        ushort4 o;
        o.x = f2bf(v.x); o.y = f2bf(v.y); o.z = f2bf(v.z); o.w = f2bf(v.w);
        *(ushort4*)&Xh[idx * 4] = o;
    }
}

// ---------------------------------------------------------------------------
// kW: transpose+convert 3 fp32 [k][j] matrices -> bf16 Wt[g][j][k].
// 64x64 tiles via LDS. grid (32, 32, 3).
// ---------------------------------------------------------------------------
__global__ __launch_bounds__(256) void kW(
    const float* __restrict__ w0, const float* __restrict__ w1, const float* __restrict__ w2,
    unsigned short* __restrict__ Wt)
{
    __shared__ unsigned short Ts[64][66];
    const int t = threadIdx.x;
    const int k0 = blockIdx.x * 64, j0 = blockIdx.y * 64, g = blockIdx.z;
    const float* __restrict__ src = (g == 0) ? w0 : (g == 1) ? w1 : w2;
    unsigned short* __restrict__ dst = Wt + (size_t)g * D * D;

#pragma unroll
    for (int q = 0; q < 4; ++q) {
        int id = q * 256 + t;
        int r = id >> 4, c4 = (id & 15) * 4;
        float4 v = *(const float4*)&src[(size_t)(k0 + r) * D + j0 + c4];
        Ts[r][c4 + 0] = f2bf(v.x);
        Ts[r][c4 + 1] = f2bf(v.y);
        Ts[r][c4 + 2] = f2bf(v.z);
        Ts[r][c4 + 3] = f2bf(v.w);
    }
    __syncthreads();
#pragma unroll
    for (int q = 0; q < 4; ++q) {
        int id = q * 256 + t;
        int jr = id >> 4, kc4 = (id & 15) * 4;
        ushort4 o;
        o.x = Ts[kc4 + 0][jr];
        o.y = Ts[kc4 + 1][jr];
        o.z = Ts[kc4 + 2][jr];
        o.w = Ts[kc4 + 3][jr];
        *(ushort4*)&dst[(size_t)(j0 + jr) * D + k0 + kc4] = o;
    }
}

// ---------------------------------------------------------------------------
// kB: parallel segment extraction + counting sort by length (desc).
// ---------------------------------------------------------------------------
__global__ void kB(const int* __restrict__ term,
                   int* __restrict__ st_sorted, int* __restrict__ n_active,
                   int* __restrict__ nseg_out, int* __restrict__ maxlen_out)
{
    __shared__ unsigned long long masks[16];
    __shared__ int hist[1025];
    __shared__ int off[1025];
    __shared__ int cur[1025];
    __shared__ int sh_maxlen;
    const int tid = threadIdx.x;
    if (tid == 0) sh_maxlen = 0;
    for (int i = tid; i < 1025; i += 256) { hist[i] = 0; cur[i] = 0; }
    __syncthreads();

    const int wid = tid >> 6;
#pragma unroll
    for (int it = 0; it < 4; ++it) {
        int t = it * 256 + tid;
        bool f = (t == 0) || (term[t] != 0);
        unsigned long long m = __ballot(f);
        if ((tid & 63) == 0) masks[it * 4 + wid] = m;
    }
    __syncthreads();

    int myt[4], mylen[4], cnt = 0;
#pragma unroll
    for (int it = 0; it < 4; ++it) {
        int t = it * 256 + tid;
        int w0 = t >> 6, b = t & 63;
        if ((masks[w0] >> b) & 1ULL) {
            int next = T;
            unsigned long long m = masks[w0] & ~((2ULL << b) - 1ULL);
            if (m) next = (w0 << 6) + __builtin_ctzll(m);
            else {
                for (int w = w0 + 1; w < 16; ++w)
                    if (masks[w]) { next = (w << 6) + __builtin_ctzll(masks[w]); break; }
            }
            int L = next - t;
            myt[cnt] = t; mylen[cnt] = L; ++cnt;
            atomicAdd(&hist[L], 1);
            atomicMax(&sh_maxlen, L);
        }
    }
    __syncthreads();
    if (tid == 0) {
        int run = 0, ml = sh_maxlen;
        for (int L = ml; L >= 1; --L) {
            off[L] = run;
            run += hist[L];
            n_active[L - 1] = run;   // #segments with len >= L == active at step L-1
        }
        nseg_out[0] = run;
        maxlen_out[0] = ml;
    }
    __syncthreads();
    for (int c = 0; c < cnt; ++c) {
        int L = mylen[c];
        int pos = off[L] + atomicAdd(&cur[L], 1);
        st_sorted[pos] = myt[c];
    }
}

// ---------------------------------------------------------------------------
// kB2: init Hh0 row p (bf16), sorted order. (fp32 carry lives in kC LDS)
// Kernel-end release flushes these to the coherence point, where kC's
// bypass H-loads read them.
// ---------------------------------------------------------------------------
__global__ void kB2(const float* __restrict__ last_state, const int* __restrict__ term,
                    const int* __restrict__ st_sorted, const int* __restrict__ nseg_p,
                    unsigned short* __restrict__ Hh0)
{
    int p = blockIdx.x;
    if (p >= nseg_p[0]) return;
    bool useLast = (st_sorted[p] == 0) && (term[0] == 0);
    for (int j = threadIdx.x; j < D; j += 256) {
        float v = useLast ? last_state[j] : 0.0f;
        Hh0[(size_t)p * D + j] = f2bf(v);
    }
}

// ---------------------------------------------------------------------------
// kA2: tiled bf16 GEMM gih = bf16(Xh @ Wi^T + bias). M=1024, N=6144, K=2048.
// ---------------------------------------------------------------------------
__global__ __launch_bounds__(256) void kA2(
    const unsigned short* __restrict__ Xh, const unsigned short* __restrict__ Wit,
    const float* __restrict__ bir, const float* __restrict__ biz, const float* __restrict__ bin,
    unsigned short* __restrict__ gih)
{
    __shared__ __align__(16) unsigned short As[128 * 32];
    __shared__ __align__(16) unsigned short Bs[128 * 32];
    const int t = threadIdx.x;
    const int lane = t & 63, wave = t >> 6;
    const int mlane = lane & 15, quad = lane >> 4;
    const int wm = wave & 1, wn = wave >> 1;
    const int n0 = blockIdx.x * 128, m0 = blockIdx.y * 128;

    f32x4 acc[4][4];
#pragma unroll
    for (int i = 0; i < 4; ++i)
#pragma unroll
        for (int j = 0; j < 4; ++j) acc[i][j] = (f32x4){0.f, 0.f, 0.f, 0.f};

    for (int k0 = 0; k0 < D; k0 += 32) {
        __syncthreads();
#pragma unroll
        for (int q = 0; q < 2; ++q) {
            int c = q * 256 + t;
            int row = c >> 2, k8 = (c & 3) * 8;
            *(bf16x8*)&As[c * 8] = *(const bf16x8*)&Xh[(size_t)(m0 + row) * D + k0 + k8];
            *(bf16x8*)&Bs[c * 8] = *(const bf16x8*)&Wit[(size_t)(n0 + row) * D + k0 + k8];
        }
        __syncthreads();
        bf16x8 a[4], b[4];
#pragma unroll
        for (int i = 0; i < 4; ++i)
            a[i] = *(const bf16x8*)&As[(wm * 64 + i * 16 + mlane) * 32 + quad * 8];
#pragma unroll
        for (int j = 0; j < 4; ++j)
            b[j] = *(const bf16x8*)&Bs[(wn * 64 + j * 16 + mlane) * 32 + quad * 8];
#pragma unroll
        for (int i = 0; i < 4; ++i)
#pragma unroll
            for (int j = 0; j < 4; ++j)
                acc[i][j] = __builtin_amdgcn_mfma_f32_16x16x32_bf16(a[i], b[j], acc[i][j], 0, 0, 0);
    }

    const int g = n0 >> 11;
    const float* __restrict__ bias = (g == 0) ? bir : (g == 1) ? biz : bin;
    float bv[4];
#pragma unroll
    for (int j = 0; j < 4; ++j)
        bv[j] = bias[(n0 & 2047) + wn * 64 + j * 16 + mlane];

#pragma unroll
    for (int i = 0; i < 4; ++i) {
#pragma unroll
        for (int j = 0; j < 4; ++j) {
            int ncol = n0 + wn * 64 + j * 16 + mlane;
#pragma unroll
            for (int r = 0; r < 4; ++r) {
                int mrow = m0 + wm * 64 + i * 16 + quad * 4 + r;
                gih[(size_t)mrow * NG + ncol] = f2bf(acc[i][j][r] + bv[j]);
            }
        }
    }
}

// ---------------------------------------------------------------------------
// gbar: flag-array grid barrier, relaxed agent-scope polls.
// R11: NO fences at all. All cross-block data (Hnxt) is written with sc0/sc1
// write-through stores (acked at the coherence point before the flag store,
// via s_waitcnt vmcnt(0)) and read with relaxed agent-scope atomic loads
// (bypass L1/L2, read the coherence point). W/gih/meta are read-only during
// the scan, so local caches can never serve stale data for them — no inv
// needed. This keeps W permanently L2-warm across all steps.
// ---------------------------------------------------------------------------
__device__ __forceinline__ void gbar(int* flags, int* release, int sval) {
    asm volatile("s_waitcnt vmcnt(0)" ::: "memory");  // sc stores acked
    __syncthreads();                                   // all waves done
    const int tid = threadIdx.x;
    if (blockIdx.x == 0) {
        if (tid > 0 && tid < (int)gridDim.x) {
            while (__hip_atomic_load(&flags[tid], __ATOMIC_RELAXED,
                                     __HIP_MEMORY_SCOPE_AGENT) != sval)
                __builtin_amdgcn_s_sleep(8);
        }
        __syncthreads();   // all flags observed
        if (tid == 0)
            __hip_atomic_store(release, sval, __ATOMIC_RELAXED,
                               __HIP_MEMORY_SCOPE_AGENT);
        __syncthreads();
    } else {
        if (tid == 0) {
            __hip_atomic_store(&flags[blockIdx.x], sval, __ATOMIC_RELAXED,
                               __HIP_MEMORY_SCOPE_AGENT);
            while (__hip_atomic_load(release, __ATOMIC_RELAXED,
                                     __HIP_MEMORY_SCOPE_AGENT) != sval)
                __builtin_amdgcn_s_sleep(8);
        }
        __syncthreads();
    }
}

// ---------------------------------------------------------------------------
// epi_tile: fused GRU gate epilogue for one 16-row C-fragment group.
// ho carry from block-private LDS (HbL). Hnxt via sc0/sc1 write-through
// (coherence-point store; paired with bypass loads on the read side).
// out via nontemporal stores (read only by host; end-of-kernel release).
// ---------------------------------------------------------------------------
__device__ __forceinline__ void epi_tile(
    f32x4 cR, f32x4 cZ, f32x4 cN, int rb, int active, int s,
    const int* __restrict__ st, const unsigned short* __restrict__ gih,
    float* HbL, unsigned short* __restrict__ Hnxt, float* __restrict__ out,
    int jcol, int mlane, float bh)
{
#pragma unroll
    for (int r = 0; r < 4; ++r) {
        int p = rb + r;
        if (p < active) {
            int tt = st[p] + s;
            size_t gbase = (size_t)tt * NG + jcol;
            float gr = bf2f(gih[gbase]);
            float gz = bf2f(gih[gbase + D]);
            float gn = bf2f(gih[gbase + 2 * D]);
            float ho = HbL[p * 16 + mlane];
            float rr = sigf(cR[r] + gr);
            float zz = sigf(cZ[r] + gz);
            float nn = tanhfast(gn + rr * (cN[r] + bh));
            float h = (1.0f - zz) * nn + zz * ho;
            HbL[p * 16 + mlane] = h;
            {
                unsigned int hv = (unsigned int)f2bf(h);
                const unsigned short* hp = &Hnxt[(size_t)p * D + jcol];
                asm volatile("global_store_short %0, %1, off sc0 sc1"
                             :: "v"(hp), "v"(hv) : "memory");
            }
            __builtin_nontemporal_store(h, &out[(size_t)tt * D + jcol]);
            __builtin_nontemporal_store(h, &out[(size_t)(T + tt) * D + jcol]);
        }
    }
}

// ---------------------------------------------------------------------------
// kC (cooperative, 128 blocks x 512 threads): fused macro-step scan.
// Identical to the passing R10 kernel except: H fragments are read via
// relaxed agent-scope atomic loads (coherence-point bypass) and gbar has
// no cache fences at all — W/gih stay L2-warm across all steps.
// ---------------------------------------------------------------------------
__global__ __launch_bounds__(512, 1) void kC(
    const unsigned short* __restrict__ Wht, const float* __restrict__ bhn,
    const unsigned short* __restrict__ gih,
    const float* __restrict__ last, const int* __restrict__ term,
    unsigned short* __restrict__ Hh0, unsigned short* __restrict__ Hh1,
    const int* __restrict__ st, const int* __restrict__ n_active,
    const int* __restrict__ nseg_p, const int* __restrict__ maxlen_p,
    int* __restrict__ flags, int* __restrict__ release,
    float* __restrict__ out)
{
    __shared__ f32x4 red[3072];      // 48 KB reduction buffer
    __shared__ float HbL[16384];     // 64 KB block-private fp32 carry [p][col]
    const int tid = threadIdx.x;
    const int lane = tid & 63, wave = tid >> 6;      // 0..7
    const int mlane = lane & 15, quad = lane >> 4;
    const int jg = blockIdx.x;           // 128 blocks, one 16-col group each
    const int jcol = jg * 16 + mlane;
    const float bh = bhn[jcol];
    const unsigned short* __restrict__ Wr = Wht + (size_t)jcol * D;
    const unsigned short* __restrict__ Wz = Wht + (size_t)(D + jcol) * D;
    const unsigned short* __restrict__ Wn = Wht + (size_t)(2 * D + jcol) * D;
    const int maxlen = maxlen_p[0];

    // init fp32 carry in LDS (matches old kB2 Hb semantics)
    {
        const int nseg = nseg_p[0];
        const int t0f = term[0];
        for (int idx = tid; idx < 16384; idx += 512) {
            int p = idx >> 4, c = idx & 15;
            float v = 0.0f;
            if (p < nseg && t0f == 0 && st[p] == 0) v = last[jg * 16 + c];
            HbL[idx] = v;
        }
    }
    __syncthreads();

    for (int s = 0; s < maxlen; ++s) {
        const unsigned short* __restrict__ Hcur = (s & 1) ? Hh1 : Hh0;
        unsigned short* __restrict__ Hnxt = (s & 1) ? Hh0 : Hh1;
        const int active = n_active[s];
        const int mtiles = (active + 15) >> 4;
        // dynamic wave split: wmc tile-groups x ksc K-slices
        const int wsh = (mtiles >= 4) ? 2 : ((mtiles >= 2) ? 1 : 0);
        const int wmc = 1 << wsh;            // 4,2,1
        const int ksc = 8 >> wsh;            // 2,4,8
        const int kspan = 8 << wsh;          // 32,16,8 = 64/ksc
        const int wm = wave & (wmc - 1);
        const int kh = wave >> wsh;
        const int kbeg = kh * kspan;

        for (int m0 = 0; m0 < mtiles; m0 += 32) {
            const int nmt = min(32, mtiles - m0);
            f32x4 aR[8], aZ[8], aN[8];
#pragma unroll
            for (int i = 0; i < 8; ++i) {
                aR[i] = (f32x4){0.f, 0.f, 0.f, 0.f};
                aZ[i] = (f32x4){0.f, 0.f, 0.f, 0.f};
                aN[i] = (f32x4){0.f, 0.f, 0.f, 0.f};
            }
            if (wm < nmt) {       // idle waves skip the whole chain
                for (int kc = kbeg; kc < kbeg + kspan; ++kc) {
                    const int koff = kc * 32 + quad * 8;
                    bf16x8 br = *(const bf16x8*)&Wr[koff];
                    bf16x8 bz = *(const bf16x8*)&Wz[koff];
                    bf16x8 bn = *(const bf16x8*)&Wn[koff];
#pragma unroll
                    for (int i = 0; i < 8; ++i) {
                        if (wm + wmc * i < nmt) {
                            bf16x8 a = ld_h_sc(&Hcur[
                                (size_t)((m0 + wm + wmc * i) * 16 + mlane) * D + koff]);
                            aR[i] = __builtin_amdgcn_mfma_f32_16x16x32_bf16(a, br, aR[i], 0, 0, 0);
                            aZ[i] = __builtin_amdgcn_mfma_f32_16x16x32_bf16(a, bz, aZ[i], 0, 0, 0);
                            aN[i] = __builtin_amdgcn_mfma_f32_16x16x32_bf16(a, bn, aN[i], 0, 0, 0);
                        }
                    }
                }
            }

            if (wmc == 4) {
                // two-round cross-kh reduction (R6-proven shape), 48 KB
                if (kh == 1) {
#pragma unroll
                    for (int i = 0; i < 4; ++i) {
                        if (wm + 4 * i < nmt) {
                            int base = ((wm * 4 + i) * 3) * 64 + lane;
                            red[base]       = aR[i];
                            red[base + 64]  = aZ[i];
                            red[base + 128] = aN[i];
                        }
                    }
                }
                __syncthreads();
                if (kh == 0) {
#pragma unroll
                    for (int i = 0; i < 4; ++i) {
                        if (wm + 4 * i < nmt) {
                            int base = ((wm * 4 + i) * 3) * 64 + lane;
                            aR[i] += red[base];
                            aZ[i] += red[base + 64];
                            aN[i] += red[base + 128];
                        }
                    }
                }
                __syncthreads();
                if (kh == 1) {
#pragma unroll
                    for (int i = 4; i < 8; ++i) {
                        if (wm + 4 * i < nmt) {
                            int base = ((wm * 4 + (i - 4)) * 3) * 64 + lane;
                            red[base]       = aR[i];
                            red[base + 64]  = aZ[i];
                            red[base + 128] = aN[i];
                        }
                    }
                }
                __syncthreads();
                if (kh == 0) {
#pragma unroll
                    for (int i = 4; i < 8; ++i) {
                        if (wm + 4 * i < nmt) {
                            int base = ((wm * 4 + (i - 4)) * 3) * 64 + lane;
                            aR[i] += red[base];
                            aZ[i] += red[base + 64];
                            aN[i] += red[base + 128];
                        }
                    }
#pragma unroll
                    for (int i = 0; i < 8; ++i) {
                        if (wm + 4 * i < nmt) {
                            int rb = (m0 + wm + 4 * i) * 16 + quad * 4;
                            epi_tile(aR[i], aZ[i], aN[i], rb, active, s,
                                     st, gih, HbL, Hnxt, out, jcol, mlane, bh);
                        }
                    }
                }
                __syncthreads();
            } else {
                // tail path: nmt <= 3, publishers kh>=1 use small slots
                if (kh >= 1) {
#pragma unroll
                    for (int i = 0; i < 8; ++i) {
                        int t = wm + wmc * i;
                        if (t < nmt) {
                            int slot = (wmc == 1) ? (kh - 1) : ((kh - 1) * 4 + t);
                            int base = (slot * 3) * 64 + lane;
                            red[base]       = aR[i];
                            red[base + 64]  = aZ[i];
                            red[base + 128] = aN[i];
                        }
                    }
                }
                __syncthreads();
                if (kh == 0) {
#pragma unroll
                    for (int i = 0; i < 8; ++i) {
                        int t = wm + wmc * i;
                        if (t < nmt) {
                            for (int kk = 1; kk < ksc; ++kk) {
                                int slot = (wmc == 1) ? (kk - 1) : ((kk - 1) * 4 + t);
                                int base = (slot * 3) * 64 + lane;
                                aR[i] += red[base];
                                aZ[i] += red[base + 64];
                                aN[i] += red[base + 128];
                            }
                            int rb = (m0 + t) * 16 + quad * 4;
                            epi_tile(aR[i], aZ[i], aN[i], rb, active, s,
                                     st, gih, HbL, Hnxt, out, jcol, mlane, bh);
                        }
                    }
                }
                __syncthreads();
            }
        }
        gbar(flags, release, s + 1);
    }
}

// ---------------------------------------------------------------------------
// Workspace layout (54.54 MB total):
//   [0,16K)  meta: st[1024] | n_active[1024] | nseg | maxlen | pad |
//            flags[128] @ int 2112 | release @ int 2304
//   +25.17M  Wbuf  bf16 [3][2048][2048]  (Wit, then OVERWRITTEN with Wht)
//   +12.58M  gih   bf16 [T][NG]
//   +8.39M   (old Hb slot, unused)
//   +4.19M   Hh0   bf16 [T][D]
//   +4.19M   Hh1   bf16 [T][D]   (head aliased as Xh; Xh dead after kA2)
// ---------------------------------------------------------------------------
extern "C" void kernel_launch(void* const* d_in, const int* in_sizes, int n_in,
                              void* d_out, int out_size, void* d_ws, size_t ws_size,
                              hipStream_t stream)
{
    const float* X    = (const float*)d_in[0];
    const int*   term = (const int*)  d_in[1];
    const float* last = (const float*)d_in[2];
    const float* wir  = (const float*)d_in[3];
    const float* wiz  = (const float*)d_in[4];
    const float* win  = (const float*)d_in[5];
    const float* bir  = (const float*)d_in[6];
    const float* biz  = (const float*)d_in[7];
    const float* bin  = (const float*)d_in[8];
    const float* whr  = (const float*)d_in[9];
    const float* whz  = (const float*)d_in[10];
    const float* whn  = (const float*)d_in[11];
    const float* bhn  = (const float*)d_in[12];
    float* out = (float*)d_out;

    char* ws = (char*)d_ws;
    int* meta = (int*)ws;
    int* st       = meta;
    int* n_active = meta + 1024;
    int* nseg_p   = meta + 2048;
    int* maxlen_p = meta + 2049;
    int* flags    = meta + 2112;
    int* release  = meta + 2304;
    size_t off = 16384;
    unsigned short* Wbuf = (unsigned short*)(ws + off); off += (size_t)3 * D * D * 2; // 25.17M
    unsigned short* gih  = (unsigned short*)(ws + off); off += (size_t)T * NG * 2;    // 12.58M
    off += (size_t)T * D * 4;                                                         // old Hb (unused)
    unsigned short* Hh0  = (unsigned short*)(ws + off); off += (size_t)T * D * 2;     // 4.19M
    unsigned short* Hh1  = (unsigned short*)(ws + off);                                // 4.19M
    unsigned short* Xh   = Hh1;   // alias: Xh dead after kA2; Hh1 first written in kC

    kX<<<512, 256, 0, stream>>>(X, Xh);
    kB<<<1, 256, 0, stream>>>(term, st, n_active, nseg_p, maxlen_p);
    kB2<<<1024, 256, 0, stream>>>(last, term, st, nseg_p, Hh0);
    kW<<<dim3(32, 32, 3), 256, 0, stream>>>(wir, wiz, win, Wbuf);     // Wit
    kA2<<<dim3(48, 8), 256, 0, stream>>>(Xh, Wbuf, bir, biz, bin, gih);
    kW<<<dim3(32, 32, 3), 256, 0, stream>>>(whr, whz, whn, Wbuf);     // Wht (overwrite)

    const unsigned short* c_wht = Wbuf; const float* c_bhn = bhn;
    const unsigned short* c_gih = gih;
    const float* c_last = last; const int* c_term = term;
    unsigned short* c_h0 = Hh0; unsigned short* c_h1 = Hh1;
    const int* c_st = st; const int* c_na = n_active;
    const int* c_ns = nseg_p; const int* c_ml = maxlen_p;
    int* c_fl = flags; int* c_rel = release; float* c_out = out;
    void* args[] = {&c_wht, &c_bhn, &c_gih, &c_last, &c_term, &c_h0, &c_h1,
                    &c_st, &c_na, &c_ns, &c_ml, &c_fl, &c_rel, &c_out};
    hipLaunchCooperativeKernel((void*)kC, dim3(KC_BLOCKS), dim3(512), args, 0, stream);
}

// Round 12
// 635.934 us; speedup vs baseline: 1.1410x; 1.1410x over previous
//
#include <hip/hip_runtime.h>

#define D 2048
#define T 1024
#define NG 6144            // 3 * D
#define KC_BLOCKS 128      // one 16-col j-group per block

typedef short bf16x8 __attribute__((ext_vector_type(8)));
typedef float f32x4 __attribute__((ext_vector_type(4)));

__device__ __forceinline__ float sigf(float x) {
    return 1.0f / (1.0f + __expf(-x));
}
__device__ __forceinline__ float tanhfast(float x) {
    float e = __expf(-2.0f * fabsf(x));
    float t = (1.0f - e) / (1.0f + e);
    return copysignf(t, x);
}
// fp32 -> bf16 round-to-nearest-even
__device__ __forceinline__ unsigned short f2bf(float x) {
    unsigned int u = __float_as_uint(x);
    return (unsigned short)((u + 0x7FFFu + ((u >> 16) & 1u)) >> 16);
}
__device__ __forceinline__ float bf2f(unsigned short h) {
    return __uint_as_float((unsigned int)h << 16);
}
// direct global->LDS 16B DMA: lds dest is wave-uniform base + lane*16
__device__ __forceinline__ void gl_lds16(const unsigned short* g, unsigned short* l) {
    __builtin_amdgcn_global_load_lds(
        (const __attribute__((address_space(1))) unsigned int*)(const void*)g,
        (__attribute__((address_space(3))) unsigned int*)(void*)l,
        16, 0, 0);
}

// ---------------------------------------------------------------------------
// kX: X fp32 -> bf16
// ---------------------------------------------------------------------------
__global__ void kX(const float* __restrict__ X, unsigned short* __restrict__ Xh) {
    int idx = blockIdx.x * 256 + threadIdx.x;
    const int total = T * D / 4;
    for (; idx < total; idx += gridDim.x * 256) {
        float4 v = *(const float4*)&X[idx * 4];
        ushort4 o;
        o.x = f2bf(v.x); o.y = f2bf(v.y); o.z = f2bf(v.z); o.w = f2bf(v.w);
        *(ushort4*)&Xh[idx * 4] = o;
    }
}

// ---------------------------------------------------------------------------
// kW: transpose+convert 3 fp32 [k][j] matrices -> bf16 Wt[g][j][k].
// 64x64 tiles via LDS. grid (32, 32, 3).
// ---------------------------------------------------------------------------
__global__ __launch_bounds__(256) void kW(
    const float* __restrict__ w0, const float* __restrict__ w1, const float* __restrict__ w2,
    unsigned short* __restrict__ Wt)
{
    __shared__ unsigned short Ts[64][66];
    const int t = threadIdx.x;
    const int k0 = blockIdx.x * 64, j0 = blockIdx.y * 64, g = blockIdx.z;
    const float* __restrict__ src = (g == 0) ? w0 : (g == 1) ? w1 : w2;
    unsigned short* __restrict__ dst = Wt + (size_t)g * D * D;

#pragma unroll
    for (int q = 0; q < 4; ++q) {
        int id = q * 256 + t;
        int r = id >> 4, c4 = (id & 15) * 4;
        float4 v = *(const float4*)&src[(size_t)(k0 + r) * D + j0 + c4];
        Ts[r][c4 + 0] = f2bf(v.x);
        Ts[r][c4 + 1] = f2bf(v.y);
        Ts[r][c4 + 2] = f2bf(v.z);
        Ts[r][c4 + 3] = f2bf(v.w);
    }
    __syncthreads();
#pragma unroll
    for (int q = 0; q < 4; ++q) {
        int id = q * 256 + t;
        int jr = id >> 4, kc4 = (id & 15) * 4;
        ushort4 o;
        o.x = Ts[kc4 + 0][jr];
        o.y = Ts[kc4 + 1][jr];
        o.z = Ts[kc4 + 2][jr];
        o.w = Ts[kc4 + 3][jr];
        *(ushort4*)&dst[(size_t)(j0 + jr) * D + k0 + kc4] = o;
    }
}

// ---------------------------------------------------------------------------
// kB: parallel segment extraction + counting sort by length (desc).
// ---------------------------------------------------------------------------
__global__ void kB(const int* __restrict__ term,
                   int* __restrict__ st_sorted, int* __restrict__ n_active,
                   int* __restrict__ nseg_out, int* __restrict__ maxlen_out)
{
    __shared__ unsigned long long masks[16];
    __shared__ int hist[1025];
    __shared__ int off[1025];
    __shared__ int cur[1025];
    __shared__ int sh_maxlen;
    const int tid = threadIdx.x;
    if (tid == 0) sh_maxlen = 0;
    for (int i = tid; i < 1025; i += 256) { hist[i] = 0; cur[i] = 0; }
    __syncthreads();

    const int wid = tid >> 6;
#pragma unroll
    for (int it = 0; it < 4; ++it) {
        int t = it * 256 + tid;
        bool f = (t == 0) || (term[t] != 0);
        unsigned long long m = __ballot(f);
        if ((tid & 63) == 0) masks[it * 4 + wid] = m;
    }
    __syncthreads();

    int myt[4], mylen[4], cnt = 0;
#pragma unroll
    for (int it = 0; it < 4; ++it) {
        int t = it * 256 + tid;
        int w0 = t >> 6, b = t & 63;
        if ((masks[w0] >> b) & 1ULL) {
            int next = T;
            unsigned long long m = masks[w0] & ~((2ULL << b) - 1ULL);
            if (m) next = (w0 << 6) + __builtin_ctzll(m);
            else {
                for (int w = w0 + 1; w < 16; ++w)
                    if (masks[w]) { next = (w << 6) + __builtin_ctzll(masks[w]); break; }
            }
            int L = next - t;
            myt[cnt] = t; mylen[cnt] = L; ++cnt;
            atomicAdd(&hist[L], 1);
            atomicMax(&sh_maxlen, L);
        }
    }
    __syncthreads();
    if (tid == 0) {
        int run = 0, ml = sh_maxlen;
        for (int L = ml; L >= 1; --L) {
            off[L] = run;
            run += hist[L];
            n_active[L - 1] = run;   // #segments with len >= L == active at step L-1
        }
        nseg_out[0] = run;
        maxlen_out[0] = ml;
    }
    __syncthreads();
    for (int c = 0; c < cnt; ++c) {
        int L = mylen[c];
        int pos = off[L] + atomicAdd(&cur[L], 1);
        st_sorted[pos] = myt[c];
    }
}

// ---------------------------------------------------------------------------
// kB2: init Hh0 row p (bf16), sorted order. (fp32 carry lives in kC LDS)
// ---------------------------------------------------------------------------
__global__ void kB2(const float* __restrict__ last_state, const int* __restrict__ term,
                    const int* __restrict__ st_sorted, const int* __restrict__ nseg_p,
                    unsigned short* __restrict__ Hh0)
{
    int p = blockIdx.x;
    if (p >= nseg_p[0]) return;
    bool useLast = (st_sorted[p] == 0) && (term[0] == 0);
    for (int j = threadIdx.x; j < D; j += 256) {
        float v = useLast ? last_state[j] : 0.0f;
        Hh0[(size_t)p * D + j] = f2bf(v);
    }
}

// ---------------------------------------------------------------------------
// kA2: tiled bf16 GEMM gih = bf16(Xh @ Wi^T + bias). M=1024, N=6144, K=2048.
// R12: staging via global_load_lds width=16 (m97 technique) — the LDS
// layout (As[c*8], c = q*256+wave*64+lane) is already the required
// wave-uniform-base + lane*16B pattern, so this is a drop-in swap.
// ---------------------------------------------------------------------------
__global__ __launch_bounds__(256) void kA2(
    const unsigned short* __restrict__ Xh, const unsigned short* __restrict__ Wit,
    const float* __restrict__ bir, const float* __restrict__ biz, const float* __restrict__ bin,
    unsigned short* __restrict__ gih)
{
    __shared__ __align__(16) unsigned short As[128 * 32];
    __shared__ __align__(16) unsigned short Bs[128 * 32];
    const int t = threadIdx.x;
    const int lane = t & 63, wave = t >> 6;
    const int mlane = lane & 15, quad = lane >> 4;
    const int wm = wave & 1, wn = wave >> 1;
    const int n0 = blockIdx.x * 128, m0 = blockIdx.y * 128;

    f32x4 acc[4][4];
#pragma unroll
    for (int i = 0; i < 4; ++i)
#pragma unroll
        for (int j = 0; j < 4; ++j) acc[i][j] = (f32x4){0.f, 0.f, 0.f, 0.f};

    for (int k0 = 0; k0 < D; k0 += 32) {
        __syncthreads();
#pragma unroll
        for (int q = 0; q < 2; ++q) {
            int c = q * 256 + t;
            int row = c >> 2, k8 = (c & 3) * 8;
            unsigned short* lA = &As[(q * 256 + wave * 64) * 8];
            unsigned short* lB = &Bs[(q * 256 + wave * 64) * 8];
            gl_lds16(&Xh[(size_t)(m0 + row) * D + k0 + k8], lA);
            gl_lds16(&Wit[(size_t)(n0 + row) * D + k0 + k8], lB);
        }
        __syncthreads();
        bf16x8 a[4], b[4];
#pragma unroll
        for (int i = 0; i < 4; ++i)
            a[i] = *(const bf16x8*)&As[(wm * 64 + i * 16 + mlane) * 32 + quad * 8];
#pragma unroll
        for (int j = 0; j < 4; ++j)
            b[j] = *(const bf16x8*)&Bs[(wn * 64 + j * 16 + mlane) * 32 + quad * 8];
#pragma unroll
        for (int i = 0; i < 4; ++i)
#pragma unroll
            for (int j = 0; j < 4; ++j)
                acc[i][j] = __builtin_amdgcn_mfma_f32_16x16x32_bf16(a[i], b[j], acc[i][j], 0, 0, 0);
    }

    const int g = n0 >> 11;
    const float* __restrict__ bias = (g == 0) ? bir : (g == 1) ? biz : bin;
    float bv[4];
#pragma unroll
    for (int j = 0; j < 4; ++j)
        bv[j] = bias[(n0 & 2047) + wn * 64 + j * 16 + mlane];

#pragma unroll
    for (int i = 0; i < 4; ++i) {
#pragma unroll
        for (int j = 0; j < 4; ++j) {
            int ncol = n0 + wn * 64 + j * 16 + mlane;
#pragma unroll
            for (int r = 0; r < 4; ++r) {
                int mrow = m0 + wm * 64 + i * 16 + quad * 4 + r;
                gih[(size_t)mrow * NG + ncol] = f2bf(acc[i][j][r] + bv[j]);
            }
        }
    }
}

// ---------------------------------------------------------------------------
// gbar: flag-array grid barrier, relaxed agent-scope polls (R9/R10-proven).
// No release wbl2 (Hnxt is sc0/sc1 write-through, acked via vmcnt(0)).
// Read-side acquire fence (inv) ONCE per step — R11 proved replacing it
// with bypass loads is worse (374 -> 467).
// ---------------------------------------------------------------------------
__device__ __forceinline__ void gbar(int* flags, int* release, int sval) {
    asm volatile("s_waitcnt vmcnt(0)" ::: "memory");  // sc stores acked
    __syncthreads();                                   // all waves done
    const int tid = threadIdx.x;
    if (blockIdx.x == 0) {
        if (tid > 0 && tid < (int)gridDim.x) {
            while (__hip_atomic_load(&flags[tid], __ATOMIC_RELAXED,
                                     __HIP_MEMORY_SCOPE_AGENT) != sval)
                __builtin_amdgcn_s_sleep(8);
        }
        __syncthreads();   // all flags observed
        if (tid == 0) {
            __builtin_amdgcn_fence(__ATOMIC_ACQUIRE, "agent"); // inv L1+L2 once
            __hip_atomic_store(release, sval, __ATOMIC_RELAXED,
                               __HIP_MEMORY_SCOPE_AGENT);
        }
        __syncthreads();
    } else {
        if (tid == 0) {
            __hip_atomic_store(&flags[blockIdx.x], sval, __ATOMIC_RELAXED,
                               __HIP_MEMORY_SCOPE_AGENT);
            while (__hip_atomic_load(release, __ATOMIC_RELAXED,
                                     __HIP_MEMORY_SCOPE_AGENT) != sval)
                __builtin_amdgcn_s_sleep(8);
            __builtin_amdgcn_fence(__ATOMIC_ACQUIRE, "agent"); // inv L1+L2 once
        }
        __syncthreads();
    }
}

// ---------------------------------------------------------------------------
// epi_tile: fused GRU gate epilogue for one 16-row C-fragment group.
// ho carry from block-private LDS (HbL). Hnxt via sc0/sc1 write-through.
// out via nontemporal stores.
// ---------------------------------------------------------------------------
__device__ __forceinline__ void epi_tile(
    f32x4 cR, f32x4 cZ, f32x4 cN, int rb, int active, int s,
    const int* __restrict__ st, const unsigned short* __restrict__ gih,
    float* HbL, unsigned short* __restrict__ Hnxt, float* __restrict__ out,
    int jcol, int mlane, float bh)
{
#pragma unroll
    for (int r = 0; r < 4; ++r) {
        int p = rb + r;
        if (p < active) {
            int tt = st[p] + s;
            size_t gbase = (size_t)tt * NG + jcol;
            float gr = bf2f(gih[gbase]);
            float gz = bf2f(gih[gbase + D]);
            float gn = bf2f(gih[gbase + 2 * D]);
            float ho = HbL[p * 16 + mlane];
            float rr = sigf(cR[r] + gr);
            float zz = sigf(cZ[r] + gz);
            float nn = tanhfast(gn + rr * (cN[r] + bh));
            float h = (1.0f - zz) * nn + zz * ho;
            HbL[p * 16 + mlane] = h;
            {
                unsigned int hv = (unsigned int)f2bf(h);
                const unsigned short* hp = &Hnxt[(size_t)p * D + jcol];
                asm volatile("global_store_short %0, %1, off sc0 sc1"
                             :: "v"(hp), "v"(hv) : "memory");
            }
            __builtin_nontemporal_store(h, &out[(size_t)tt * D + jcol]);
            __builtin_nontemporal_store(h, &out[(size_t)(T + tt) * D + jcol]);
        }
    }
}

// ---------------------------------------------------------------------------
// kC (cooperative, 128 blocks x 512 threads): fused macro-step scan.
// Byte-identical to the passing R10 kernel (best measured: 374us).
// ---------------------------------------------------------------------------
__global__ __launch_bounds__(512, 1) void kC(
    const unsigned short* __restrict__ Wht, const float* __restrict__ bhn,
    const unsigned short* __restrict__ gih,
    const float* __restrict__ last, const int* __restrict__ term,
    unsigned short* __restrict__ Hh0, unsigned short* __restrict__ Hh1,
    const int* __restrict__ st, const int* __restrict__ n_active,
    const int* __restrict__ nseg_p, const int* __restrict__ maxlen_p,
    int* __restrict__ flags, int* __restrict__ release,
    float* __restrict__ out)
{
    __shared__ f32x4 red[3072];      // 48 KB reduction buffer
    __shared__ float HbL[16384];     // 64 KB block-private fp32 carry [p][col]
    const int tid = threadIdx.x;
    const int lane = tid & 63, wave = tid >> 6;      // 0..7
    const int mlane = lane & 15, quad = lane >> 4;
    const int jg = blockIdx.x;           // 128 blocks, one 16-col group each
    const int jcol = jg * 16 + mlane;
    const float bh = bhn[jcol];
    const unsigned short* __restrict__ Wr = Wht + (size_t)jcol * D;
    const unsigned short* __restrict__ Wz = Wht + (size_t)(D + jcol) * D;
    const unsigned short* __restrict__ Wn = Wht + (size_t)(2 * D + jcol) * D;
    const int maxlen = maxlen_p[0];

    // init fp32 carry in LDS (matches old kB2 Hb semantics)
    {
        const int nseg = nseg_p[0];
        const int t0f = term[0];
        for (int idx = tid; idx < 16384; idx += 512) {
            int p = idx >> 4, c = idx & 15;
            float v = 0.0f;
            if (p < nseg && t0f == 0 && st[p] == 0) v = last[jg * 16 + c];
            HbL[idx] = v;
        }
    }
    __syncthreads();

    for (int s = 0; s < maxlen; ++s) {
        const unsigned short* __restrict__ Hcur = (s & 1) ? Hh1 : Hh0;
        unsigned short* __restrict__ Hnxt = (s & 1) ? Hh0 : Hh1;
        const int active = n_active[s];
        const int mtiles = (active + 15) >> 4;
        // dynamic wave split: wmc tile-groups x ksc K-slices
        const int wsh = (mtiles >= 4) ? 2 : ((mtiles >= 2) ? 1 : 0);
        const int wmc = 1 << wsh;            // 4,2,1
        const int ksc = 8 >> wsh;            // 2,4,8
        const int kspan = 8 << wsh;          // 32,16,8 = 64/ksc
        const int wm = wave & (wmc - 1);
        const int kh = wave >> wsh;
        const int kbeg = kh * kspan;

        for (int m0 = 0; m0 < mtiles; m0 += 32) {
            const int nmt = min(32, mtiles - m0);
            f32x4 aR[8], aZ[8], aN[8];
#pragma unroll
            for (int i = 0; i < 8; ++i) {
                aR[i] = (f32x4){0.f, 0.f, 0.f, 0.f};
                aZ[i] = (f32x4){0.f, 0.f, 0.f, 0.f};
                aN[i] = (f32x4){0.f, 0.f, 0.f, 0.f};
            }
            if (wm < nmt) {       // idle waves skip the whole chain
                for (int kc = kbeg; kc < kbeg + kspan; ++kc) {
                    const int koff = kc * 32 + quad * 8;
                    bf16x8 br = *(const bf16x8*)&Wr[koff];
                    bf16x8 bz = *(const bf16x8*)&Wz[koff];
                    bf16x8 bn = *(const bf16x8*)&Wn[koff];
#pragma unroll
                    for (int i = 0; i < 8; ++i) {
                        if (wm + wmc * i < nmt) {
                            bf16x8 a = *(const bf16x8*)&Hcur[
                                (size_t)((m0 + wm + wmc * i) * 16 + mlane) * D + koff];
                            aR[i] = __builtin_amdgcn_mfma_f32_16x16x32_bf16(a, br, aR[i], 0, 0, 0);
                            aZ[i] = __builtin_amdgcn_mfma_f32_16x16x32_bf16(a, bz, aZ[i], 0, 0, 0);
                            aN[i] = __builtin_amdgcn_mfma_f32_16x16x32_bf16(a, bn, aN[i], 0, 0, 0);
                        }
                    }
                }
            }

            if (wmc == 4) {
                // two-round cross-kh reduction (R6-proven shape), 48 KB
                if (kh == 1) {
#pragma unroll
                    for (int i = 0; i < 4; ++i) {
                        if (wm + 4 * i < nmt) {
                            int base = ((wm * 4 + i) * 3) * 64 + lane;
                            red[base]       = aR[i];
                            red[base + 64]  = aZ[i];
                            red[base + 128] = aN[i];
                        }
                    }
                }
                __syncthreads();
                if (kh == 0) {
#pragma unroll
                    for (int i = 0; i < 4; ++i) {
                        if (wm + 4 * i < nmt) {
                            int base = ((wm * 4 + i) * 3) * 64 + lane;
                            aR[i] += red[base];
                            aZ[i] += red[base + 64];
                            aN[i] += red[base + 128];
                        }
                    }
                }
                __syncthreads();
                if (kh == 1) {
#pragma unroll
                    for (int i = 4; i < 8; ++i) {
                        if (wm + 4 * i < nmt) {
                            int base = ((wm * 4 + (i - 4)) * 3) * 64 + lane;
                            red[base]       = aR[i];
                            red[base + 64]  = aZ[i];
                            red[base + 128] = aN[i];
                        }
                    }
                }
                __syncthreads();
                if (kh == 0) {
#pragma unroll
                    for (int i = 4; i < 8; ++i) {
                        if (wm + 4 * i < nmt) {
                            int base = ((wm * 4 + (i - 4)) * 3) * 64 + lane;
                            aR[i] += red[base];
                            aZ[i] += red[base + 64];
                            aN[i] += red[base + 128];
                        }
                    }
#pragma unroll
                    for (int i = 0; i < 8; ++i) {
                        if (wm + 4 * i < nmt) {
                            int rb = (m0 + wm + 4 * i) * 16 + quad * 4;
                            epi_tile(aR[i], aZ[i], aN[i], rb, active, s,
                                     st, gih, HbL, Hnxt, out, jcol, mlane, bh);
                        }
                    }
                }
                __syncthreads();
            } else {
                // tail path: nmt <= 3, publishers kh>=1 use small slots
                if (kh >= 1) {
#pragma unroll
                    for (int i = 0; i < 8; ++i) {
                        int t = wm + wmc * i;
                        if (t < nmt) {
                            int slot = (wmc == 1) ? (kh - 1) : ((kh - 1) * 4 + t);
                            int base = (slot * 3) * 64 + lane;
                            red[base]       = aR[i];
                            red[base + 64]  = aZ[i];
                            red[base + 128] = aN[i];
                        }
                    }
                }
                __syncthreads();
                if (kh == 0) {
#pragma unroll
                    for (int i = 0; i < 8; ++i) {
                        int t = wm + wmc * i;
                        if (t < nmt) {
                            for (int kk = 1; kk < ksc; ++kk) {
                                int slot = (wmc == 1) ? (kk - 1) : ((kk - 1) * 4 + t);
                                int base = (slot * 3) * 64 + lane;
                                aR[i] += red[base];
                                aZ[i] += red[base + 64];
                                aN[i] += red[base + 128];
                            }
                            int rb = (m0 + t) * 16 + quad * 4;
                            epi_tile(aR[i], aZ[i], aN[i], rb, active, s,
                                     st, gih, HbL, Hnxt, out, jcol, mlane, bh);
                        }
                    }
                }
                __syncthreads();
            }
        }
        gbar(flags, release, s + 1);
    }
}

// ---------------------------------------------------------------------------
// Workspace layout (54.54 MB total):
//   [0,16K)  meta: st[1024] | n_active[1024] | nseg | maxlen | pad |
//            flags[128] @ int 2112 | release @ int 2304
//   +25.17M  Wbuf  bf16 [3][2048][2048]  (Wit, then OVERWRITTEN with Wht)
//   +12.58M  gih   bf16 [T][NG]
//   +8.39M   (old Hb slot, unused)
//   +4.19M   Hh0   bf16 [T][D]
//   +4.19M   Hh1   bf16 [T][D]   (head aliased as Xh; Xh dead after kA2)
// ---------------------------------------------------------------------------
extern "C" void kernel_launch(void* const* d_in, const int* in_sizes, int n_in,
                              void* d_out, int out_size, void* d_ws, size_t ws_size,
                              hipStream_t stream)
{
    const float* X    = (const float*)d_in[0];
    const int*   term = (const int*)  d_in[1];
    const float* last = (const float*)d_in[2];
    const float* wir  = (const float*)d_in[3];
    const float* wiz  = (const float*)d_in[4];
    const float* win  = (const float*)d_in[5];
    const float* bir  = (const float*)d_in[6];
    const float* biz  = (const float*)d_in[7];
    const float* bin  = (const float*)d_in[8];
    const float* whr  = (const float*)d_in[9];
    const float* whz  = (const float*)d_in[10];
    const float* whn  = (const float*)d_in[11];
    const float* bhn  = (const float*)d_in[12];
    float* out = (float*)d_out;

    char* ws = (char*)d_ws;
    int* meta = (int*)ws;
    int* st       = meta;
    int* n_active = meta + 1024;
    int* nseg_p   = meta + 2048;
    int* maxlen_p = meta + 2049;
    int* flags    = meta + 2112;
    int* release  = meta + 2304;
    size_t off = 16384;
    unsigned short* Wbuf = (unsigned short*)(ws + off); off += (size_t)3 * D * D * 2; // 25.17M
    unsigned short* gih  = (unsigned short*)(ws + off); off += (size_t)T * NG * 2;    // 12.58M
    off += (size_t)T * D * 4;                                                         // old Hb (unused)
    unsigned short* Hh0  = (unsigned short*)(ws + off); off += (size_t)T * D * 2;     // 4.19M
    unsigned short* Hh1  = (unsigned short*)(ws + off);                                // 4.19M
    unsigned short* Xh   = Hh1;   // alias: Xh dead after kA2; Hh1 first written in kC

    kX<<<512, 256, 0, stream>>>(X, Xh);
    kB<<<1, 256, 0, stream>>>(term, st, n_active, nseg_p, maxlen_p);
    kB2<<<1024, 256, 0, stream>>>(last, term, st, nseg_p, Hh0);
    kW<<<dim3(32, 32, 3), 256, 0, stream>>>(wir, wiz, win, Wbuf);     // Wit
    kA2<<<dim3(48, 8), 256, 0, stream>>>(Xh, Wbuf, bir, biz, bin, gih);
    kW<<<dim3(32, 32, 3), 256, 0, stream>>>(whr, whz, whn, Wbuf);     // Wht (overwrite)

    const unsigned short* c_wht = Wbuf; const float* c_bhn = bhn;
    const unsigned short* c_gih = gih;
    const float* c_last = last; const int* c_term = term;
    unsigned short* c_h0 = Hh0; unsigned short* c_h1 = Hh1;
    const int* c_st = st; const int* c_na = n_active;
    const int* c_ns = nseg_p; const int* c_ml = maxlen_p;
    int* c_fl = flags; int* c_rel = release; float* c_out = out;
    void* args[] = {&c_wht, &c_bhn, &c_gih, &c_last, &c_term, &c_h0, &c_h1,
                    &c_st, &c_na, &c_ns, &c_ml, &c_fl, &c_rel, &c_out};
    hipLaunchCooperativeKernel((void*)kC, dim3(KC_BLOCKS), dim3(512), args, 0, stream);
}